// Round 1
// baseline (707.293 us; speedup 1.0000x reference)
//
#include <hip/hip_runtime.h>
#include <hip/hip_bf16.h>
#include <stdint.h>

#define NSTARTS 4096
#define NCLS    32768
#define EDIM    128
#define FDIM    256

typedef __attribute__((ext_vector_type(8))) short bf16x8;   // 8 bf16 = 4 VGPR
typedef __attribute__((ext_vector_type(4))) float f32x4;    // MFMA C/D

static __device__ __forceinline__ ushort f2bf(float x) {
    union { float f; uint32_t u; } v; v.f = x;
    uint32_t r = v.u + 0x7FFF + ((v.u >> 16) & 1);  // RNE
    return (ushort)(r >> 16);
}
static __device__ __forceinline__ float bf2f(ushort x) {
    union { uint32_t u; float f; } v; v.u = ((uint32_t)x) << 16; return v.f;
}
static __device__ __forceinline__ void gload_lds16(const void* g, void* l) {
    __builtin_amdgcn_global_load_lds(
        (const __attribute__((address_space(1))) void*)g,
        (__attribute__((address_space(3))) void*)l, 16, 0, 0);
}

// ---------------- prep: projT bf16 [FDIM][EDIM], zero w ----------------
__global__ __launch_bounds__(256) void prep_kernel(
    const float* __restrict__ proj, ushort* __restrict__ projT, float* __restrict__ w) {
    int k = blockIdx.x;    // 0..127
    int n = threadIdx.x;   // 0..255
    projT[n * EDIM + k] = f2bf(proj[k * FDIM + n]);
    if (k == 0) w[n] = 0.0f;
}

// ---------------- pass1: E = X@proj, row-max, expE=exp(E-m) bf16, mE ----------------
// grid = M/128 blocks, 512 threads (8 waves: 2 row-groups x 4 col-groups of 64x64)
__global__ __launch_bounds__(512) void pass1_kernel(
    const float* __restrict__ X, const ushort* __restrict__ projT,
    ushort* __restrict__ expE, float* __restrict__ mE) {
    __shared__ ushort lA[128 * 136];        // A tile bf16, padded stride 136
    __shared__ float smax[128][4];
    int tid = threadIdx.x;
    int mBase = blockIdx.x * 128;

    // stage X (f32) -> bf16 LDS, 128x128
    #pragma unroll
    for (int i = 0; i < 8; ++i) {
        int idx4 = tid + i * 512;          // float4 index 0..4095
        int e = idx4 << 2;
        int r = e >> 7, c = e & 127;
        float4 v = *(const float4*)&X[(size_t)(mBase + r) * EDIM + c];
        ushort4 u; u.x = f2bf(v.x); u.y = f2bf(v.y); u.z = f2bf(v.z); u.w = f2bf(v.w);
        *(ushort4*)&lA[r * 136 + c] = u;
    }
    __syncthreads();

    int w8 = tid >> 6, l = tid & 63;
    int wr = w8 >> 2, wc = w8 & 3;          // wave -> (row 64-blk, col 64-blk)
    int lr = l & 15, lg = l >> 4;

    f32x4 acc[4][4];
    #pragma unroll
    for (int mi = 0; mi < 4; ++mi)
        #pragma unroll
        for (int ni = 0; ni < 4; ++ni)
            acc[mi][ni] = (f32x4){0.f, 0.f, 0.f, 0.f};

    #pragma unroll
    for (int kk = 0; kk < 4; ++kk) {        // K=128 in 4 steps of 32
        bf16x8 af[4], bfr[4];
        #pragma unroll
        for (int mi = 0; mi < 4; ++mi)
            af[mi] = *(const bf16x8*)&lA[(wr * 64 + mi * 16 + lr) * 136 + kk * 32 + lg * 8];
        #pragma unroll
        for (int ni = 0; ni < 4; ++ni)
            bfr[ni] = *(const bf16x8*)&projT[(size_t)(wc * 64 + ni * 16 + lr) * EDIM + kk * 32 + lg * 8];
        #pragma unroll
        for (int mi = 0; mi < 4; ++mi)
            #pragma unroll
            for (int ni = 0; ni < 4; ++ni)
                acc[mi][ni] = __builtin_amdgcn_mfma_f32_16x16x32_bf16(af[mi], bfr[ni], acc[mi][ni], 0, 0, 0);
    }

    // per-lane row max over this wave's 64 cols, then cross-wave via LDS
    float rm[4][4];
    #pragma unroll
    for (int mi = 0; mi < 4; ++mi)
        #pragma unroll
        for (int j = 0; j < 4; ++j) {
            float m = acc[mi][0][j];
            m = fmaxf(m, acc[mi][1][j]);
            m = fmaxf(m, acc[mi][2][j]);
            m = fmaxf(m, acc[mi][3][j]);
            #pragma unroll
            for (int off = 1; off < 16; off <<= 1)
                m = fmaxf(m, __shfl_xor(m, off, 64));
            rm[mi][j] = m;
        }
    if (lr == 0) {
        #pragma unroll
        for (int mi = 0; mi < 4; ++mi)
            #pragma unroll
            for (int j = 0; j < 4; ++j)
                smax[wr * 64 + mi * 16 + lg * 4 + j][wc] = rm[mi][j];
    }
    __syncthreads();

    if (tid < 128) {
        float m = fmaxf(fmaxf(smax[tid][0], smax[tid][1]), fmaxf(smax[tid][2], smax[tid][3]));
        mE[mBase + tid] = m;
    }

    #pragma unroll
    for (int mi = 0; mi < 4; ++mi)
        #pragma unroll
        for (int j = 0; j < 4; ++j) {
            int rl = wr * 64 + mi * 16 + lg * 4 + j;
            float m = fmaxf(fmaxf(smax[rl][0], smax[rl][1]), fmaxf(smax[rl][2], smax[rl][3]));
            #pragma unroll
            for (int ni = 0; ni < 4; ++ni) {
                float e = __expf(acc[mi][ni][j] - m);
                expE[(size_t)(mBase + rl) * FDIM + wc * 64 + ni * 16 + lr] = f2bf(e);
            }
        }
}

// ---------------- wsum: w[f] = sum_j expR[j,f] * e^{mR[j]} ----------------
__global__ __launch_bounds__(256) void wsum_kernel(
    const ushort* __restrict__ expR, const float* __restrict__ mR, float* __restrict__ w) {
    __shared__ float emr[256];
    int t = threadIdx.x;
    int rbase = blockIdx.x * 256;
    emr[t] = __expf(mR[rbase + t]);
    __syncthreads();
    float acc = 0.f;
    #pragma unroll 8
    for (int r = 0; r < 256; ++r)
        acc += bf2f(expR[(size_t)(rbase + r) * FDIM + t]) * emr[r];
    atomicAdd(&w[t], acc);
}

// ---------------- lro: lro[i] = log(sum_f expL[i,f]*w[f]) ----------------
__global__ __launch_bounds__(256) void lro_kernel(
    const ushort* __restrict__ expL, const float* __restrict__ w, float* __restrict__ lro) {
    int wid = threadIdx.x >> 6, l = threadIdx.x & 63;
    int row = blockIdx.x * 4 + wid;
    float acc = 0.f;
    #pragma unroll
    for (int c = 0; c < 4; ++c) {
        int f = c * 64 + l;
        acc += bf2f(expL[(size_t)row * FDIM + f]) * w[f];
    }
    #pragma unroll
    for (int off = 32; off; off >>= 1) acc += __shfl_xor(acc, off, 64);
    if (l == 0) lro[row] = __logf(acc);
}

// ---------------- main GEMM: out[i,j] = (log S + mR[j] - lro[i]) / temp ----------------
// 128x128 tile, 256 threads (4 waves 2x2 of 64x64), BK=64, global_load_lds width 16
__global__ __launch_bounds__(256) void gemm_kernel(
    const ushort* __restrict__ expL, const ushort* __restrict__ expR,
    const float* __restrict__ mR, const float* __restrict__ lro,
    const float* __restrict__ temp, float* __restrict__ out) {
    __shared__ ushort lA[128 * 64];
    __shared__ ushort lB[128 * 64];
    int tid = threadIdx.x;
    int w8 = tid >> 6, l = tid & 63;
    int wr = w8 >> 1, wc = w8 & 1;
    int lr = l & 15, lg = l >> 4;
    int nBase = blockIdx.x * 128, mBase = blockIdx.y * 128;

    f32x4 acc[4][4];
    #pragma unroll
    for (int mi = 0; mi < 4; ++mi)
        #pragma unroll
        for (int ni = 0; ni < 4; ++ni)
            acc[mi][ni] = (f32x4){0.f, 0.f, 0.f, 0.f};

    for (int kt = 0; kt < 4; ++kt) {        // K=256, 4 tiles of 64
        #pragma unroll
        for (int i = 0; i < 4; ++i) {
            int chunk = i * 4 + w8;          // 0..15, wave-uniform
            int elem = (chunk << 9) + l * 8; // linear bf16 index into 128x64 tile
            int r = elem >> 6, c = elem & 63;
            gload_lds16(expL + (size_t)(mBase + r) * FDIM + kt * 64 + c, &lA[chunk << 9]);
            gload_lds16(expR + (size_t)(nBase + r) * FDIM + kt * 64 + c, &lB[chunk << 9]);
        }
        __syncthreads();
        #pragma unroll
        for (int kk = 0; kk < 2; ++kk) {
            bf16x8 af[4], bfr[4];
            #pragma unroll
            for (int mi = 0; mi < 4; ++mi)
                af[mi] = *(const bf16x8*)&lA[(wr * 64 + mi * 16 + lr) * 64 + kk * 32 + lg * 8];
            #pragma unroll
            for (int ni = 0; ni < 4; ++ni)
                bfr[ni] = *(const bf16x8*)&lB[(wc * 64 + ni * 16 + lr) * 64 + kk * 32 + lg * 8];
            #pragma unroll
            for (int mi = 0; mi < 4; ++mi)
                #pragma unroll
                for (int ni = 0; ni < 4; ++ni)
                    acc[mi][ni] = __builtin_amdgcn_mfma_f32_16x16x32_bf16(af[mi], bfr[ni], acc[mi][ni], 0, 0, 0);
        }
        __syncthreads();
    }

    float invt = 1.0f / temp[0];
    #pragma unroll
    for (int ni = 0; ni < 4; ++ni) {
        int col = nBase + wc * 64 + ni * 16 + lr;
        float mRc = mR[col];
        #pragma unroll
        for (int mi = 0; mi < 4; ++mi) {
            f32x4 a = acc[mi][ni];
            #pragma unroll
            for (int j = 0; j < 4; ++j) {
                int row = mBase + wr * 64 + mi * 16 + lg * 4 + j;
                out[(size_t)row * NCLS + col] = (__logf(a[j]) + mRc - lro[row]) * invt;
            }
        }
    }
}

extern "C" void kernel_launch(void* const* d_in, const int* in_sizes, int n_in,
                              void* d_out, int out_size, void* d_ws, size_t ws_size,
                              hipStream_t stream) {
    const float* start_emb  = (const float*)d_in[0];
    const float* output_emb = (const float*)d_in[1];
    const float* proj       = (const float*)d_in[2];
    const float* temp       = (const float*)d_in[3];
    float* out = (float*)d_out;

    uintptr_t p = (uintptr_t)d_ws;
    ushort* projT = (ushort*)p; p += (size_t)FDIM * EDIM * 2;      // 64 KB
    float*  wvec  = (float*)p;  p += (size_t)FDIM * 4;             // 1 KB
    ushort* expL  = (ushort*)p; p += (size_t)NSTARTS * FDIM * 2;   // 2 MB
    float*  mL    = (float*)p;  p += (size_t)NSTARTS * 4;          // 16 KB (unused downstream)
    ushort* expR  = (ushort*)p; p += (size_t)NCLS * FDIM * 2;      // 16 MB
    float*  mR    = (float*)p;  p += (size_t)NCLS * 4;             // 128 KB
    float*  lro   = (float*)p;  p += (size_t)NSTARTS * 4;          // 16 KB

    prep_kernel <<<dim3(EDIM),        dim3(FDIM), 0, stream>>>(proj, projT, wvec);
    pass1_kernel<<<dim3(NSTARTS/128), dim3(512),  0, stream>>>(start_emb,  projT, expL, mL);
    pass1_kernel<<<dim3(NCLS/128),    dim3(512),  0, stream>>>(output_emb, projT, expR, mR);
    wsum_kernel <<<dim3(NCLS/256),    dim3(256),  0, stream>>>(expR, mR, wvec);
    lro_kernel  <<<dim3(NSTARTS/4),   dim3(256),  0, stream>>>(expL, wvec, lro);
    gemm_kernel <<<dim3(NCLS/128, NSTARTS/128), dim3(256), 0, stream>>>(expL, expR, mR, lro, temp, out);
}